// Round 4
// baseline (4935.482 us; speedup 1.0000x reference)
//
#include <hip/hip_runtime.h>
#include <math.h>
#include <stdint.h>

#define NN 500000
#define NE 16000000
#define NT 62                     // dst tiles of 8192 nodes (dst >> 13)
#define NQ 8                      // src octants of 62500 (src / 62500, exact 8 ranges)
#define OCTW 62500
#define NCH (NT * NQ)             // 496 chunks
#define PB 65536                  // edges per partition block
#define NPB ((NE + PB - 1) / PB)  // 245
#define CH_CAP 34000              // chunk cap: mean 32258, sigma~180, +9.7 sigma
#define ZPAD 524288               // z sized past sentinel src 0x7FFFF
#define SENT 0xFFFFFFFFu          // sentinel edge: dlo=8191, src=0x7FFFF -> z==0

// ---------------- phase 1: chunk histogram ----------------
__global__ __launch_bounds__(1024) void hist_kernel(const int4* __restrict__ src4,
                                                    const int4* __restrict__ dst4,
                                                    int* __restrict__ bcnt) {
    __shared__ int lh[NCH];
    for (int i = threadIdx.x; i < NCH; i += 1024) lh[i] = 0;
    __syncthreads();
    long base4 = (long)blockIdx.x * (PB / 4);
    for (int k = 0; k < PB / 4; k += 1024) {
        long i4 = base4 + k + threadIdx.x;
        if (i4 < NE / 4) {
            int4 d = dst4[i4];
            int4 s = src4[i4];
            atomicAdd(&lh[(d.x >> 13) * NQ + s.x / OCTW], 1);
            atomicAdd(&lh[(d.y >> 13) * NQ + s.y / OCTW], 1);
            atomicAdd(&lh[(d.z >> 13) * NQ + s.z / OCTW], 1);
            atomicAdd(&lh[(d.w >> 13) * NQ + s.w / OCTW], 1);
        }
    }
    __syncthreads();
    for (int i = threadIdx.x; i < NCH; i += 1024) {
        int c = lh[i];
        if (c) atomicAdd(&bcnt[i], c);
    }
}

// ---------------- phase 2: padded exclusive scan (496 chunks, one tile) ----
// Chunk bases padded to multiples of 16 edges (64B) so scatter_kernel can use
// uint4 loads on line-aligned ranges; gaps are SENT-filled by chunk_sort.
__global__ __launch_bounds__(512) void scan_buckets(const int* __restrict__ bcnt,
                                                    int* __restrict__ bbase,
                                                    int* __restrict__ bcur) {
    __shared__ int scn[512];
    __shared__ int tot;
    int i = threadIdx.x;
    int v = (i < NCH) ? bcnt[i] : 0;
    int pv = (v + 15) & ~15;
    scn[i] = pv;
    __syncthreads();
    for (int off = 1; off < 512; off <<= 1) {
        int t = (i >= off) ? scn[i - off] : 0;
        __syncthreads();
        scn[i] += t;
        __syncthreads();
    }
    int excl = scn[i] - pv;
    if (i < NCH) { bbase[i] = excl; bcur[i] = excl; }
    if (i == 511) tot = scn[511];
    __syncthreads();
    if (i == 0) bbase[NCH] = tot;   // padded total <= NE + 496*15
}

// ---------------- phase 3: partition edges into 496 chunks ----------------
// word = (dst&8191)<<19 | src.  Runs per bucket per block = 65536/496 ~ 132
// edges = 528B -> near-full-line writes (kills the 388MB write amp).
__global__ __launch_bounds__(1024) void partition_kernel(const int4* __restrict__ src4,
                                                         const int4* __restrict__ dst4,
                                                         int* __restrict__ bcur,
                                                         uint32_t* __restrict__ ebuf) {
    __shared__ int lh[NCH];
    for (int i = threadIdx.x; i < NCH; i += 1024) lh[i] = 0;
    __syncthreads();
    long base4 = (long)blockIdx.x * (PB / 4);
    for (int k = 0; k < PB / 4; k += 1024) {
        long i4 = base4 + k + threadIdx.x;
        if (i4 < NE / 4) {
            int4 d = dst4[i4];
            int4 s = src4[i4];
            atomicAdd(&lh[(d.x >> 13) * NQ + s.x / OCTW], 1);
            atomicAdd(&lh[(d.y >> 13) * NQ + s.y / OCTW], 1);
            atomicAdd(&lh[(d.z >> 13) * NQ + s.z / OCTW], 1);
            atomicAdd(&lh[(d.w >> 13) * NQ + s.w / OCTW], 1);
        }
    }
    __syncthreads();
    for (int i = threadIdx.x; i < NCH; i += 1024) {
        int c = lh[i];
        if (c) lh[i] = atomicAdd(&bcur[i], c);   // reserve run; lh becomes cursor
    }
    __syncthreads();
    for (int k = 0; k < PB / 4; k += 1024) {
        long i4 = base4 + k + threadIdx.x;
        if (i4 < NE / 4) {
            int4 d = dst4[i4];
            int4 s = src4[i4];
            int pos;
            pos = atomicAdd(&lh[(d.x >> 13) * NQ + s.x / OCTW], 1);
            ebuf[pos] = ((uint32_t)(d.x & 8191) << 19) | (uint32_t)s.x;
            pos = atomicAdd(&lh[(d.y >> 13) * NQ + s.y / OCTW], 1);
            ebuf[pos] = ((uint32_t)(d.y & 8191) << 19) | (uint32_t)s.y;
            pos = atomicAdd(&lh[(d.z >> 13) * NQ + s.z / OCTW], 1);
            ebuf[pos] = ((uint32_t)(d.z & 8191) << 19) | (uint32_t)s.z;
            pos = atomicAdd(&lh[(d.w >> 13) * NQ + s.w / OCTW], 1);
            ebuf[pos] = ((uint32_t)(d.w & 8191) << 19) | (uint32_t)s.w;
        }
    }
}

// ---------------- phase 4: per-chunk line-granularity sort + degree -------
// Sort chunk edges by src-line (src>>4) so a wave's consecutive edges in
// scatter_kernel span ~8 z-lines (8.26 edges/line density) instead of 64.
// Counting sort fully in LDS; writes back IN PLACE, sentinel-fills padding.
// Also accumulates per-dst degree (coalesced global int atomics).
// LDS: 136000 + 16384 + 4096 = 156480 B < 160 KiB.
__global__ __launch_bounds__(1024) void chunk_sort(const int* __restrict__ bcnt,
                                                   const int* __restrict__ bbase,
                                                   uint32_t* __restrict__ ebuf,
                                                   int* __restrict__ deg) {
    __shared__ uint32_t sorted[CH_CAP];   // first 8192 ints reused as deg hist
    __shared__ int ghist[4096];           // 3907 src-line granules used
    __shared__ int scn[1024];
    int c = blockIdx.x;
    int base = bbase[c];
    int pend = bbase[c + 1];
    int n = bcnt[c];
    if (n > CH_CAP) n = CH_CAP;           // p < 1e-10; guards LDS
    int t = c >> 3;
    int octbase = (c & 7) * OCTW;
    int* dh = (int*)sorted;               // 8192 degree counters (pre-pass2 only)
    for (int i = threadIdx.x; i < 4096; i += 1024) ghist[i] = 0;
    for (int i = threadIdx.x; i < 8192; i += 1024) dh[i] = 0;
    __syncthreads();
    for (int i = threadIdx.x; i < n; i += 1024) {
        uint32_t w = ebuf[base + i];
        int s = (int)(w & 0x7FFFFu);
        atomicAdd(&ghist[(s - octbase) >> 4], 1);
        atomicAdd(&dh[w >> 19], 1);
    }
    __syncthreads();
    for (int i = threadIdx.x; i < 8192; i += 1024) {
        int d = dh[i];
        if (d) atomicAdd(&deg[t * 8192 + i], d);
    }
    __syncthreads();
    // exclusive scan of ghist (1024 threads x 4 counters)
    int b4 = threadIdx.x * 4;
    int l0 = ghist[b4], l1 = ghist[b4 + 1], l2 = ghist[b4 + 2], l3 = ghist[b4 + 3];
    int ls = l0 + l1 + l2 + l3;
    scn[threadIdx.x] = ls;
    __syncthreads();
    for (int off = 1; off < 1024; off <<= 1) {
        int tv = (threadIdx.x >= off) ? scn[threadIdx.x - off] : 0;
        __syncthreads();
        scn[threadIdx.x] += tv;
        __syncthreads();
    }
    int ex = scn[threadIdx.x] - ls;
    ghist[b4] = ex; ghist[b4 + 1] = ex + l0;
    ghist[b4 + 2] = ex + l0 + l1; ghist[b4 + 3] = ex + l0 + l1 + l2;
    __syncthreads();
    // pass 2: scatter into LDS sorted buffer (overwrites dh region - done)
    for (int i = threadIdx.x; i < n; i += 1024) {
        uint32_t w = ebuf[base + i];
        int k = ((int)(w & 0x7FFFFu) - octbase) >> 4;
        int pos = atomicAdd(&ghist[k], 1);
        sorted[pos] = w;
    }
    __syncthreads();
    // coalesced write-back, sentinel-fill the 16-alignment padding
    for (int i = threadIdx.x; base + i < pend; i += 1024)
        ebuf[base + i] = (i < n) ? sorted[i] : SENT;
}

__global__ void dis_kernel(const int* __restrict__ deg, const float* __restrict__ x0,
                           float* __restrict__ dis, float* __restrict__ z0) {
    int v = blockIdx.x * 512 + threadIdx.x;
    if (v < NN) {
        float d = rsqrtf((float)(deg[v] + 1));   // +1 self loop
        dis[v] = d;
        z0[v] = x0[v] * d;
    }
}

// ---------------- per-layer A: src-clustered scatter into LDS partials ----
// Block = chunk (t,q). uint4 edge reads (16B/lane, coalesced); a lane's 4
// consecutive sorted edges usually share a z-line -> its 4 gathers touch
// 1-2 lines. acc[dlo] += z[src] via LDS float atomics; flush owned partial
// coalesced (no global float atomics; combine sums partials in fixed order).
__global__ __launch_bounds__(1024) void scatter_kernel(const int* __restrict__ bbase,
                                                       const uint32_t* __restrict__ ebuf,
                                                       const float* __restrict__ zin,
                                                       float* __restrict__ hp) {
    __shared__ float acc[8192];
    int c = blockIdx.x;
    for (int i = threadIdx.x; i < 8192; i += 1024) acc[i] = 0.f;
    __syncthreads();
    int b4 = bbase[c] >> 2, e4 = bbase[c + 1] >> 2;    // 16-edge padded -> /4 exact
    const uint4* __restrict__ eb4 = (const uint4*)ebuf;
    for (int i4 = b4 + threadIdx.x; i4 < e4; i4 += 1024) {
        uint4 w = eb4[i4];
        float a0 = zin[w.x & 0x7FFFFu];
        float a1 = zin[w.y & 0x7FFFFu];
        float a2 = zin[w.z & 0x7FFFFu];
        float a3 = zin[w.w & 0x7FFFFu];
        atomicAdd(&acc[w.x >> 19], a0);
        atomicAdd(&acc[w.y >> 19], a1);
        atomicAdd(&acc[w.z >> 19], a2);
        atomicAdd(&acc[w.w >> 19], a3);
    }
    __syncthreads();
    int t = c >> 3, q = c & 7;
    float* dstp = hp + (size_t)q * (NT * 8192) + t * 8192;
    for (int k = threadIdx.x; k < 8192; k += 1024) dstp[k] = acc[k];
}

// ---------------- per-layer B: combine partials + activation (float4) -----
__global__ __launch_bounds__(512) void combine_kernel(const float4* __restrict__ hp4,
        const float4* __restrict__ zin4, const float4* __restrict__ dis4,
        const float4* __restrict__ x04, const float* __restrict__ w,
        int li, int act, float4* __restrict__ zout4, int4* __restrict__ out4) {
    int v4 = blockIdx.x * 512 + threadIdx.x;            // NN/4 = 125000 units
    if (v4 >= NN / 4) return;
    float4 s = zin4[v4];                                // self loop
    #pragma unroll
    for (int q = 0; q < NQ; q++) {
        float4 hq = hp4[(size_t)q * (NT * 8192 / 4) + v4];
        s.x += hq.x; s.y += hq.y; s.z += hq.z; s.w += hq.w;
    }
    float4 dv = dis4[v4];
    float4 xv = x04[v4];
    float wl = w[li];
    float y0 = (0.7f * dv.x * s.x + 0.3f * xv.x) * wl;
    float y1 = (0.7f * dv.y * s.y + 0.3f * xv.y) * wl;
    float y2 = (0.7f * dv.z * s.z + 0.3f * xv.z) * wl;
    float y3 = (0.7f * dv.w * s.w + 0.3f * xv.w) * wl;
    if (act == 4) {
        int4 o;
        o.x = (int)(500000.f / (1.f + expf(-y0)));
        o.y = (int)(500000.f / (1.f + expf(-y1)));
        o.z = (int)(500000.f / (1.f + expf(-y2)));
        o.w = (int)(500000.f / (1.f + expf(-y3)));
        out4[v4] = o;
        return;
    }
    float r0, r1, r2, r3;
    if (act == 0)      { r0 = y0; r1 = y1; r2 = y2; r3 = y3; }
    else if (act == 1) { r0 = fmaxf(y0, 0.f); r1 = fmaxf(y1, 0.f);
                         r2 = fmaxf(y2, 0.f); r3 = fmaxf(y3, 0.f); }
    else if (act == 2) { r0 = (y0 > 0.f) ? y0 : 0.01f * y0;
                         r1 = (y1 > 0.f) ? y1 : 0.01f * y1;
                         r2 = (y2 > 0.f) ? y2 : 0.01f * y2;
                         r3 = (y3 > 0.f) ? y3 : 0.01f * y3; }
    else               { r0 = 1.f / (1.f + expf(-y0)); r1 = 1.f / (1.f + expf(-y1));
                         r2 = 1.f / (1.f + expf(-y2)); r3 = 1.f / (1.f + expf(-y3)); }
    float4 zo;
    zo.x = dv.x * r0; zo.y = dv.y * r1; zo.z = dv.z * r2; zo.w = dv.w * r3;
    zout4[v4] = zo;
}

// ---------------- launch ----------------
extern "C" void kernel_launch(void* const* d_in, const int* in_sizes, int n_in,
                              void* d_out, int out_size, void* d_ws, size_t ws_size,
                              hipStream_t stream) {
    const float* x0  = (const float*)d_in[0];
    const float* w   = (const float*)d_in[1];
    const int*   adj = (const int*)d_in[2];             // int32 (jax demotes int64)
    const int*   src = adj;
    const int*   dst = adj + NE;
    int* out = (int*)d_out;

    uintptr_t p = (uintptr_t)d_ws;
    auto alloc = [&](size_t bytes) -> void* {
        p = (p + 255) & ~(uintptr_t)255;
        void* r = (void*)p;
        p += bytes;
        return r;
    };
    float* dis   = (float*)alloc((size_t)NN * 4);
    float* z0    = (float*)alloc((size_t)ZPAD * 4);     // padded: sentinel reads z[0x7FFFF]=0
    float* z1    = (float*)alloc((size_t)ZPAD * 4);
    int*   bcnt  = (int*)alloc((size_t)NCH * 4);
    int*   bbase = (int*)alloc((size_t)(NCH + 1) * 4);
    int*   bcur  = (int*)alloc((size_t)NCH * 4);
    uint32_t* csr = (uint32_t*)alloc(((size_t)NE + 8192) * 4);  // padded chunks
    float* hp    = (float*)alloc((size_t)NQ * NT * 8192 * 4);   // 16.25MB partials
    int*   deg   = (int*)hp;   // alias: deg dead before first hp write
    (void)ws_size;

    hipMemsetAsync(bcnt, 0, (size_t)NCH * 4, stream);
    hipMemsetAsync(deg, 0, (size_t)NT * 8192 * 4, stream);
    hipMemsetAsync(z0, 0, (size_t)ZPAD * 4, stream);    // zero tails (sentinel target)
    hipMemsetAsync(z1, 0, (size_t)ZPAD * 4, stream);

    hist_kernel<<<NPB, 1024, 0, stream>>>((const int4*)src, (const int4*)dst, bcnt);
    scan_buckets<<<1, 512, 0, stream>>>(bcnt, bbase, bcur);
    partition_kernel<<<NPB, 1024, 0, stream>>>((const int4*)src, (const int4*)dst, bcur, csr);
    chunk_sort<<<NCH, 1024, 0, stream>>>(bcnt, bbase, csr, deg);
    dis_kernel<<<(NN + 511) / 512, 512, 0, stream>>>(deg, x0, dis, z0);

    float* zbuf[2] = {z0, z1};
    const int CB = (NN / 4 + 511) / 512;                // 245
    for (int i = 0; i < 49; i++) {
        int act;
        if (i == 0)            act = 0;
        else if (i == 48)      act = 4;
        else if (i % 10 == 1)  act = 2;                 // leaky {1,11,21,31,41}
        else if (i % 10 == 4)  act = 3;                 // sigmoid {4,14,24,34,44}
        else                   act = 1;                 // relu
        scatter_kernel<<<NCH, 1024, 0, stream>>>(bbase, csr, zbuf[i & 1], hp);
        combine_kernel<<<CB, 512, 0, stream>>>((const float4*)hp, (const float4*)zbuf[i & 1],
                                               (const float4*)dis, (const float4*)x0, w,
                                               i, act, (float4*)zbuf[(i + 1) & 1], (int4*)out);
    }
}